// Round 11
// baseline (253.982 us; speedup 1.0000x reference)
//
#include <hip/hip_runtime.h>
#include <math.h>

// ---------------------------------------------------------------------------
// BitNet-style MNIST forward, STRICT-FP32, tie-neutralized act-quant (R14),
// R22 phase-split kernels, R23 fc shuffle-reduce. R25:
//  * R24 (conflict-free narrow-LDS layouts, 6 blk/CU) REVERTED: conflicts
//    fell 8.0e6 -> 2.6e5 and 6 blocks fit, yet occupancy stayed ~45% and
//    perf tracked the +8% instruction count (140.7 vs 135.7us). With R19's
//    null too: conv is ISSUE/LATENCY-bound; occupancy & <=2-way conflicts
//    are non-levers. R23's float4 layout = fewest instructions = reverted to.
//  * conv __launch_bounds__ (256,8) -> (256,4): at 48 VGPR the stage-C loop
//    can't software-pipeline (each (ic,kh)'s 4 LDS + 3 weight loads drain
//    before their 36-FMA block). 128-VGPR budget lets the compiler prefetch
//    next iteration during FMAs. Occupancy 5->4 blocks if VGPR>64 - proven
//    irrelevant (R19/R24). Worst case compiler keeps 48 VGPR = exact R23.
//  * fc_kernel / wq_kernel VERBATIM from R23.
// ---------------------------------------------------------------------------

#define OFF_W1   0        // 16 oc x 12      = 192   ([oc][k], k padded 9->12)
#define OFF_W1B  192      // 16 oc x 16 x 12 = 3072  ([oc][ic*12+k])
#define OFF_W2   3264     // 96*1*12*12 = 13824 (TRANSPOSED: [k=144][96 oc])
#define OFF_F1   17088    // 64*96      = 6144  (TRANSPOSED: [k=96][64 o])
#define OFF_F2   23232    // 64*64      = 4096  (TRANSPOSED: [k=64][64 o])
#define OFF_F3   27328    // 64*64      = 4096  (TRANSPOSED: [k=64][64 o])
#define OFF_FL   31424    // 10*64      = 640   (TRANSPOSED: [k=64][10 o])
#define OFF_V96  32768    // 8192 x 96 activation slab (phase handoff)

#define EPS_TIE  3e-5f    // code-units half-width of the tie band

// Tie-neutralized quantized real value for v >= 0 (post-ReLU / normed >= 0).
__device__ __forceinline__ float quantq(float v, float s) {
    const float u  = __fmul_rn(v, s);
    const float fl = floorf(u);
    const float fr = __fsub_rn(u, fl);                 // exact
    float q;
    if (fabsf(__fsub_rn(fr, 0.5f)) < EPS_TIE) q = __fadd_rn(fl, 0.5f);
    else                                      q = rintf(u);
    q = fminf(q, 127.f);
    return __fdiv_rn(q, s);
}

// numpy pairwise leaf (n <= 128): 8 unrolled accumulators over |p[i]|.
__device__ __forceinline__ float leaf_abs_sum(const float* __restrict__ p, int n) {
    float r[8];
    #pragma unroll
    for (int j = 0; j < 8; ++j) r[j] = fabsf(p[j]);
    const int nb = n & ~7;
    for (int i = 8; i < nb; i += 8) {
        #pragma unroll
        for (int j = 0; j < 8; ++j) r[j] = __fadd_rn(r[j], fabsf(p[i + j]));
    }
    float c = __fadd_rn(__fadd_rn(__fadd_rn(r[0], r[1]), __fadd_rn(r[2], r[3])),
                        __fadd_rn(__fadd_rn(r[4], r[5]), __fadd_rn(r[6], r[7])));
    for (int i = nb; i < n; ++i) c = __fadd_rn(c, fabsf(p[i]));
    return c;
}

// ---------------------------------------------------------------------------
// Weight quantization: 7 blocks, one per tensor. (unchanged from R16/R22)
// ---------------------------------------------------------------------------
__global__ __launch_bounds__(256) void wq_kernel(
    const float* __restrict__ w1, const float* __restrict__ w1b,
    const float* __restrict__ w2, const float* __restrict__ f1,
    const float* __restrict__ f2, const float* __restrict__ f3,
    const float* __restrict__ fl, float* __restrict__ ws)
{
    __shared__ float red[256];
    __shared__ float ls[128];
    const int blk = blockIdx.x, t = threadIdx.x;

    const float* src; int n; int mode; int off; int K; int W;
    switch (blk) {
        case 0:  src = w1;  n = 144;   mode = 0; off = OFF_W1;  K = 0;   W = 0;  break;
        case 1:  src = w1b; n = 2304;  mode = 0; off = OFF_W1B; K = 0;   W = 0;  break;
        case 2:  src = w2;  n = 13824; mode = 1; off = OFF_W2;  K = 144; W = 96; break;
        case 3:  src = f1;  n = 6144;  mode = 1; off = OFF_F1;  K = 96;  W = 64; break;
        case 4:  src = f2;  n = 4096;  mode = 1; off = OFF_F2;  K = 64;  W = 64; break;
        case 5:  src = f3;  n = 4096;  mode = 1; off = OFF_F3;  K = 64;  W = 64; break;
        default: src = fl;  n = 640;   mode = 1; off = OFF_FL;  K = 64;  W = 10; break;
    }

    if (mode == 0) {
        float p = 0.f;
        for (int i = t; i < n; i += 256) p = fmaxf(p, fabsf(src[i]));
        red[t] = p;
        __syncthreads();
        for (int s = 128; s > 0; s >>= 1) {
            if (t < s) red[t] = fmaxf(red[t], red[t + s]);
            __syncthreads();
        }
        const float s = __fdiv_rn(127.0f, fmaxf(red[0], 1e-5f));
        for (int i = t; i < n; i += 256) {
            float q = rintf(__fmul_rn(src[i], s));
            q = fminf(fmaxf(q, -128.f), 127.f);
            int d;
            if (blk == 0) d = (i / 9) * 12 + (i % 9);
            else          { const int oc = i / 144, k = i % 144;
                            d = oc * 192 + (k / 9) * 12 + (k % 9); }
            ws[off + d] = __fdiv_rn(q, s);
        }
    } else {
        int nleaf, loff, lsz;
        switch (n) {
            case 13824: nleaf = 128; loff = (t >> 1) * 216 + (t & 1) * 104;
                        lsz = (t & 1) ? 112 : 104; break;
            case 6144:  nleaf = 64;  loff = t * 96;  lsz = 96;  break;
            case 4096:  nleaf = 32;  loff = t * 128; lsz = 128; break;
            default:    nleaf = 8;   loff = t * 80;  lsz = 80;  break;  // 640
        }
        if (t < nleaf) ls[t] = leaf_abs_sum(src + loff, lsz);
        __syncthreads();
        for (int m = nleaf >> 1; m >= 1; m >>= 1) {
            float v = 0.f;
            if (t < m) v = __fadd_rn(ls[2 * t], ls[2 * t + 1]);
            __syncthreads();
            if (t < m) ls[t] = v;
            __syncthreads();
        }
        const float alpha = __fdiv_rn(ls[0], (float)n);
        for (int i = t; i < n; i += 256) {
            const float w = src[i];
            const float sg = (w > 0.f) ? 1.f : ((w < 0.f) ? -1.f : 0.f);
            const int d = (i % K) * W + (i / K);
            ws[off + d] = __fmul_rn(sg, alpha);
        }
    }
}

// ---------------------------------------------------------------------------
// conv_kernel: stages A-D, one image per block (R23 layout), writes v96 to
// the handoff slab. LDS 29,184 B. __launch_bounds__(256,4): 128-VGPR budget
// for software pipelining; occupancy 4 blocks/CU if VGPR>64 (proven non-lever).
// ---------------------------------------------------------------------------
__global__ __launch_bounds__(256, 4) void conv_kernel(
    const float* __restrict__ x, float* __restrict__ ws)
{
    __shared__ __align__(16) float s_x[16][20];        //  1280 B
    __shared__ __align__(16) float s_h1[16][14][20];   // 17920 B
    __shared__ float s_h2[16 * 156];                   //  9984 B (stride-13 rows)

    const int b = blockIdx.x;
    const int t = threadIdx.x;

    // ---- Stage A: input act-quant (accumulation-free -> hard round) ----
    {
        const float v = x[b * 256 + t];
        float m = fabsf(v);
        #pragma unroll
        for (int msk = 8; msk >= 1; msk >>= 1) m = fmaxf(m, __shfl_xor(m, msk, 16));
        const float s = __fdiv_rn(127.0f, fmaxf(m, 1e-5f));
        float q = rintf(__fmul_rn(v, s));
        q = fminf(fmaxf(q, -128.f), 127.f);
        s_x[t >> 4][t & 15] = __fdiv_rn(q, s);
    }
    __syncthreads();

    // ---- Stage B: conv1 (1->16, 3x3) + ReLU + row quant ----
    if (t < 224) {
        const int oc = t / 14, oh = t % 14;
        const float* __restrict__ wg = ws + OFF_W1 + oc * 12;
        const float4 wv0 = *(const float4*)&wg[0];
        const float4 wv1 = *(const float4*)&wg[4];
        const float  w8  = wg[8];
        const float wr[9] = {wv0.x, wv0.y, wv0.z, wv0.w,
                             wv1.x, wv1.y, wv1.z, wv1.w, w8};
        float acc[14];
        #pragma unroll
        for (int ow = 0; ow < 14; ++ow) acc[ow] = 0.f;
        #pragma unroll
        for (int kh = 0; kh < 3; ++kh) {
            float A[16];
            *(float4*)&A[0]  = *(const float4*)&s_x[oh + kh][0];
            *(float4*)&A[4]  = *(const float4*)&s_x[oh + kh][4];
            *(float4*)&A[8]  = *(const float4*)&s_x[oh + kh][8];
            *(float4*)&A[12] = *(const float4*)&s_x[oh + kh][12];
            #pragma unroll
            for (int kw = 0; kw < 3; ++kw) {
                const float wk = wr[kh * 3 + kw];
                #pragma unroll
                for (int ow = 0; ow < 14; ++ow)
                    acc[ow] = __fmaf_rn(A[ow + kw], wk, acc[ow]);
            }
        }
        float mx = 0.f;
        #pragma unroll
        for (int ow = 0; ow < 14; ++ow) { acc[ow] = fmaxf(acc[ow], 0.f); mx = fmaxf(mx, acc[ow]); }
        const float s = __fdiv_rn(127.0f, fmaxf(mx, 1e-5f));
        float q[14];
        #pragma unroll
        for (int ow = 0; ow < 14; ++ow) q[ow] = quantq(acc[ow], s);
        *(float4*)&s_h1[oc][oh][0]  = *(const float4*)&q[0];
        *(float4*)&s_h1[oc][oh][4]  = *(const float4*)&q[4];
        *(float4*)&s_h1[oc][oh][8]  = *(const float4*)&q[8];
        *(float2*)&s_h1[oc][oh][12] = *(const float2*)&q[12];
    }
    __syncthreads();

    // ---- Stage C: conv1b (16->16, 3x3) + ReLU + row quant ----
    if (t < 192) {
        const int oc = t / 12, oh = t % 12;
        const float* __restrict__ wg = ws + OFF_W1B + oc * 192;
        float acc[12];
        #pragma unroll
        for (int i = 0; i < 12; ++i) acc[i] = 0.f;
        for (int ic = 0; ic < 16; ++ic) {
            const float4 wv0 = *(const float4*)&wg[ic * 12];
            const float4 wv1 = *(const float4*)&wg[ic * 12 + 4];
            const float  w8  = wg[ic * 12 + 8];
            const float wr[9] = {wv0.x, wv0.y, wv0.z, wv0.w,
                                 wv1.x, wv1.y, wv1.z, wv1.w, w8};
            #pragma unroll
            for (int kh = 0; kh < 3; ++kh) {
                float A[14];
                *(float4*)&A[0]  = *(const float4*)&s_h1[ic][oh + kh][0];
                *(float4*)&A[4]  = *(const float4*)&s_h1[ic][oh + kh][4];
                *(float4*)&A[8]  = *(const float4*)&s_h1[ic][oh + kh][8];
                *(float2*)&A[12] = *(const float2*)&s_h1[ic][oh + kh][12];
                #pragma unroll
                for (int kw = 0; kw < 3; ++kw) {
                    const float w = wr[kh * 3 + kw];
                    #pragma unroll
                    for (int ow = 0; ow < 12; ++ow)
                        acc[ow] = __fmaf_rn(A[ow + kw], w, acc[ow]);
                }
            }
        }
        float mx = 0.f;
        #pragma unroll
        for (int ow = 0; ow < 12; ++ow) { acc[ow] = fmaxf(acc[ow], 0.f); mx = fmaxf(mx, acc[ow]); }
        const float s = __fdiv_rn(127.0f, fmaxf(mx, 1e-5f));
        const int hb = oc * 156 + oh * 13;
        #pragma unroll
        for (int ow = 0; ow < 12; ++ow)
            s_h2[hb + ow] = quantq(acc[ow], s);
    }
    __syncthreads();

    // ---- Stage D: conv2 grouped binary (16 g x 6 oc, 12x12) + ReLU ----
    if (t < 96) {
        const int g = t / 6;
        const float* __restrict__ wp = ws + OFF_W2;  // [k=144][96 oc]
        float acc = 0.f;
        #pragma unroll
        for (int r = 0; r < 12; ++r) {
            const int hb = g * 156 + r * 13;
            #pragma unroll
            for (int c = 0; c < 12; ++c)
                acc = __fmaf_rn(s_h2[hb + c], wp[(r * 12 + c) * 96 + t], acc);
        }
        ws[OFF_V96 + b * 96 + t] = fmaxf(acc, 0.f);   // global handoff
    }
}

// ---------------------------------------------------------------------------
// fc_kernel: 4 waves per block, each wave owns one image; mean-reduce done
// in-register via shfl chains preserving the exact numpy-pairwise order.
// LDS 1,536 B. (R23 verbatim)
// ---------------------------------------------------------------------------
__global__ __launch_bounds__(256) void fc_kernel(
    const float* __restrict__ ws, float* __restrict__ out, int nimg)
{
    __shared__ float s_q[4][96];

    const int t = threadIdx.x;
    const int w = t >> 6;      // wave id = image slot
    const int l = t & 63;      // lane within wave
    const int j = l & 7;       // r8 slot this lane reproduces
    const int img = blockIdx.x * 4 + w;
    if (img >= nimg) return;

    const float* __restrict__ v96 = ws + OFF_V96 + img * 96;

    // ---- Stage E: fc1 (96->64) ----
    float u;   // current activation vector element (lane l holds element l)
    {
        const float va = v96[l];
        const float vb = (l < 32) ? v96[64 + l] : 0.f;
        const float asq = __fmul_rn(va, va);     // t96[l]
        const float bsq = __fmul_rn(vb, vb);     // t96[64+l] (valid l<32)
        // r8[j] = t[j] + t[j+8] + ... + t[j+88], serial left-assoc (exact order):
        float r = __shfl(asq, j, 64);
        #pragma unroll
        for (int m2 = 1; m2 < 8; ++m2) r = __fadd_rn(r, __shfl(asq, j + 8 * m2, 64));
        #pragma unroll
        for (int m2 = 0; m2 < 4; ++m2) r = __fadd_rn(r, __shfl(bsq, j + 8 * m2, 64));
        // c = ((r0+r1)+(r2+r3)) + ((r4+r5)+(r6+r7)) via commutative butterfly:
        float c = __fadd_rn(r, __shfl_xor(r, 1, 64));
        c = __fadd_rn(c, __shfl_xor(c, 2, 64));
        c = __fadd_rn(c, __shfl_xor(c, 4, 64));
        const float mean = __fdiv_rn(c, 96.0f);
        const float bc1 = __fdiv_rn(1.0f, __fsqrt_rn(__fadd_rn(mean, 1e-6f)));
        const float n0 = __fmul_rn(va, bc1);
        const float n1 = __fmul_rn(vb, bc1);       // valid for l<32
        float m = n0;
        if (l < 32) m = fmaxf(m, n1);
        #pragma unroll
        for (int msk = 32; msk >= 1; msk >>= 1) m = fmaxf(m, __shfl_xor(m, msk, 64));
        const float s2 = __fdiv_rn(127.0f, fmaxf(m, 1e-5f));
        s_q[w][l] = quantq(n0, s2);
        if (l < 32) s_q[w][64 + l] = quantq(n1, s2);
        const float* __restrict__ wp = ws + OFF_F1;  // [k=96][64 o]
        float acc = 0.f;
        for (int k = 0; k < 96; ++k) acc = __fmaf_rn(s_q[w][k], wp[k * 64 + l], acc);
        u = fmaxf(acc, 0.f);
    }

    // ---- Stages F,G: fc2, fc3 (64->64) ----
    #pragma unroll 1
    for (int stage = 0; stage < 2; ++stage) {
        const int woff = stage == 0 ? OFF_F2 : OFF_F3;
        const float usq = __fmul_rn(u, u);
        // r8[j] = t[j] + t[j+8] + ... + t[j+56], serial left-assoc:
        float r = __shfl(usq, j, 64);
        #pragma unroll
        for (int m2 = 1; m2 < 8; ++m2) r = __fadd_rn(r, __shfl(usq, j + 8 * m2, 64));
        float c = __fadd_rn(r, __shfl_xor(r, 1, 64));
        c = __fadd_rn(c, __shfl_xor(c, 2, 64));
        c = __fadd_rn(c, __shfl_xor(c, 4, 64));
        const float mean = __fdiv_rn(c, 64.0f);
        const float bc1 = __fdiv_rn(1.0f, __fsqrt_rn(__fadd_rn(mean, 1e-6f)));
        const float n0 = __fmul_rn(u, bc1);
        float m = n0;
        #pragma unroll
        for (int msk = 32; msk >= 1; msk >>= 1) m = fmaxf(m, __shfl_xor(m, msk, 64));
        const float s2 = __fdiv_rn(127.0f, fmaxf(m, 1e-5f));
        s_q[w][l] = quantq(n0, s2);
        const float* __restrict__ wp = ws + woff;    // [k=64][64 o]
        float acc = 0.f;
        for (int k = 0; k < 64; ++k) acc = __fmaf_rn(s_q[w][k], wp[k * 64 + l], acc);
        u = fmaxf(acc, 0.f);
    }

    // ---- Stage H: fcl (64->10), no ReLU ----
    {
        const float usq = __fmul_rn(u, u);
        float r = __shfl(usq, j, 64);
        #pragma unroll
        for (int m2 = 1; m2 < 8; ++m2) r = __fadd_rn(r, __shfl(usq, j + 8 * m2, 64));
        float c = __fadd_rn(r, __shfl_xor(r, 1, 64));
        c = __fadd_rn(c, __shfl_xor(c, 2, 64));
        c = __fadd_rn(c, __shfl_xor(c, 4, 64));
        const float mean = __fdiv_rn(c, 64.0f);
        const float bc1 = __fdiv_rn(1.0f, __fsqrt_rn(__fadd_rn(mean, 1e-6f)));
        const float n0 = __fmul_rn(u, bc1);
        float m = n0;
        #pragma unroll
        for (int msk = 32; msk >= 1; msk >>= 1) m = fmaxf(m, __shfl_xor(m, msk, 64));
        const float s2 = __fdiv_rn(127.0f, fmaxf(m, 1e-5f));
        s_q[w][l] = quantq(n0, s2);
        const int to = (l < 10) ? l : 9;             // clamp: avoid OOB reads
        const float* __restrict__ wp = ws + OFF_FL;  // [k=64][10 o]
        float acc = 0.f;
        for (int k = 0; k < 64; ++k) acc = __fmaf_rn(s_q[w][k], wp[k * 10 + to], acc);
        if (l < 10) out[img * 10 + l] = acc;
    }
}

extern "C" void kernel_launch(void* const* d_in, const int* in_sizes, int n_in,
                              void* d_out, int out_size, void* d_ws, size_t ws_size,
                              hipStream_t stream) {
    const float* x   = (const float*)d_in[0];
    const float* w1  = (const float*)d_in[1];
    const float* w1b = (const float*)d_in[2];
    const float* w2  = (const float*)d_in[3];
    const float* f1  = (const float*)d_in[4];
    const float* f2  = (const float*)d_in[5];
    const float* f3  = (const float*)d_in[6];
    const float* fl  = (const float*)d_in[7];
    float* out = (float*)d_out;
    float* ws  = (float*)d_ws;

    const int B = in_sizes[0] / 256;  // 8192

    wq_kernel<<<7, 256, 0, stream>>>(w1, w1b, w2, f1, f2, f3, fl, ws);
    conv_kernel<<<B, 256, 0, stream>>>(x, ws);
    fc_kernel<<<(B + 3) / 4, 256, 0, stream>>>(ws, out, B);
}

// Round 12
// 227.369 us; speedup vs baseline: 1.1170x; 1.1170x over previous
//
#include <hip/hip_runtime.h>
#include <math.h>

// ---------------------------------------------------------------------------
// BitNet-style MNIST forward, STRICT-FP32, tie-neutralized act-quant (R14),
// R22 phase-split kernels, R23 fc shuffle-reduce. R26:
//  * conv_kernel REVERTED to R23 exact (__launch_bounds__(256,8)): R25 showed
//    (256,4) degrades LDS-instruction codegen (conflicts 8.0e6 -> 3.6e7 at
//    the SAME 48 VGPRs = the whole 38us regression). (256,8) is load-bearing
//    for codegen, not occupancy. Conv ledger closed: occupancy (R19/R24),
//    narrow LDS (R24), reg headroom (R25) all null -> 135.7us @80% VALUBusy
//    is conv's structural plateau.
//  * wq_kernel binary blocks: LDS-STAGE the tensor first (coalesced copy,
//    w2 = 55KB <= 64KB static; 1 block/tensor so occupancy irrelevant), then
//    leaf scan + quant/write read from LDS. The old path had each thread
//    serially walking ~108 floats at lane-stride 216 (64 cache lines per
//    load inst, ~200cy L2 latency in a serial chain) ON THE CRITICAL PATH
//    before conv can launch. Same indices/order/values -> bit-identical.
// ---------------------------------------------------------------------------

#define OFF_W1   0        // 16 oc x 12      = 192   ([oc][k], k padded 9->12)
#define OFF_W1B  192      // 16 oc x 16 x 12 = 3072  ([oc][ic*12+k])
#define OFF_W2   3264     // 96*1*12*12 = 13824 (TRANSPOSED: [k=144][96 oc])
#define OFF_F1   17088    // 64*96      = 6144  (TRANSPOSED: [k=96][64 o])
#define OFF_F2   23232    // 64*64      = 4096  (TRANSPOSED: [k=64][64 o])
#define OFF_F3   27328    // 64*64      = 4096  (TRANSPOSED: [k=64][64 o])
#define OFF_FL   31424    // 10*64      = 640   (TRANSPOSED: [k=64][10 o])
#define OFF_V96  32768    // 8192 x 96 activation slab (phase handoff)

#define EPS_TIE  3e-5f    // code-units half-width of the tie band

// Tie-neutralized quantized real value for v >= 0 (post-ReLU / normed >= 0).
__device__ __forceinline__ float quantq(float v, float s) {
    const float u  = __fmul_rn(v, s);
    const float fl = floorf(u);
    const float fr = __fsub_rn(u, fl);                 // exact
    float q;
    if (fabsf(__fsub_rn(fr, 0.5f)) < EPS_TIE) q = __fadd_rn(fl, 0.5f);
    else                                      q = rintf(u);
    q = fminf(q, 127.f);
    return __fdiv_rn(q, s);
}

// numpy pairwise leaf (n <= 128): 8 unrolled accumulators over |p[i]|.
__device__ __forceinline__ float leaf_abs_sum(const float* __restrict__ p, int n) {
    float r[8];
    #pragma unroll
    for (int j = 0; j < 8; ++j) r[j] = fabsf(p[j]);
    const int nb = n & ~7;
    for (int i = 8; i < nb; i += 8) {
        #pragma unroll
        for (int j = 0; j < 8; ++j) r[j] = __fadd_rn(r[j], fabsf(p[i + j]));
    }
    float c = __fadd_rn(__fadd_rn(__fadd_rn(r[0], r[1]), __fadd_rn(r[2], r[3])),
                        __fadd_rn(__fadd_rn(r[4], r[5]), __fadd_rn(r[6], r[7])));
    for (int i = nb; i < n; ++i) c = __fadd_rn(c, fabsf(p[i]));
    return c;
}

// ---------------------------------------------------------------------------
// Weight quantization: 7 blocks, one per tensor. Binary blocks LDS-staged
// (R26); values and destinations identical to R16/R22.
// ---------------------------------------------------------------------------
__global__ __launch_bounds__(256) void wq_kernel(
    const float* __restrict__ w1, const float* __restrict__ w1b,
    const float* __restrict__ w2, const float* __restrict__ f1,
    const float* __restrict__ f2, const float* __restrict__ f3,
    const float* __restrict__ fl, float* __restrict__ ws)
{
    __shared__ float red[256];
    __shared__ float ls[128];
    __shared__ float s_src[13824];   // 55,296 B staging (largest: w2)
    const int blk = blockIdx.x, t = threadIdx.x;

    const float* src; int n; int mode; int off; int K; int W;
    switch (blk) {
        case 0:  src = w1;  n = 144;   mode = 0; off = OFF_W1;  K = 0;   W = 0;  break;
        case 1:  src = w1b; n = 2304;  mode = 0; off = OFF_W1B; K = 0;   W = 0;  break;
        case 2:  src = w2;  n = 13824; mode = 1; off = OFF_W2;  K = 144; W = 96; break;
        case 3:  src = f1;  n = 6144;  mode = 1; off = OFF_F1;  K = 96;  W = 64; break;
        case 4:  src = f2;  n = 4096;  mode = 1; off = OFF_F2;  K = 64;  W = 64; break;
        case 5:  src = f3;  n = 4096;  mode = 1; off = OFF_F3;  K = 64;  W = 64; break;
        default: src = fl;  n = 640;   mode = 1; off = OFF_FL;  K = 64;  W = 10; break;
    }

    if (mode == 0) {
        float p = 0.f;
        for (int i = t; i < n; i += 256) p = fmaxf(p, fabsf(src[i]));
        red[t] = p;
        __syncthreads();
        for (int s = 128; s > 0; s >>= 1) {
            if (t < s) red[t] = fmaxf(red[t], red[t + s]);
            __syncthreads();
        }
        const float s = __fdiv_rn(127.0f, fmaxf(red[0], 1e-5f));
        for (int i = t; i < n; i += 256) {
            float q = rintf(__fmul_rn(src[i], s));
            q = fminf(fmaxf(q, -128.f), 127.f);
            int d;
            if (blk == 0) d = (i / 9) * 12 + (i % 9);
            else          { const int oc = i / 144, k = i % 144;
                            d = oc * 192 + (k / 9) * 12 + (k % 9); }
            ws[off + d] = __fdiv_rn(q, s);
        }
    } else {
        // R26: coalesced stage into LDS, then all reads come from LDS.
        for (int i = t; i < n; i += 256) s_src[i] = src[i];
        __syncthreads();

        int nleaf, loff, lsz;
        switch (n) {
            case 13824: nleaf = 128; loff = (t >> 1) * 216 + (t & 1) * 104;
                        lsz = (t & 1) ? 112 : 104; break;
            case 6144:  nleaf = 64;  loff = t * 96;  lsz = 96;  break;
            case 4096:  nleaf = 32;  loff = t * 128; lsz = 128; break;
            default:    nleaf = 8;   loff = t * 80;  lsz = 80;  break;  // 640
        }
        if (t < nleaf) ls[t] = leaf_abs_sum(s_src + loff, lsz);
        __syncthreads();
        for (int m = nleaf >> 1; m >= 1; m >>= 1) {
            float v = 0.f;
            if (t < m) v = __fadd_rn(ls[2 * t], ls[2 * t + 1]);
            __syncthreads();
            if (t < m) ls[t] = v;
            __syncthreads();
        }
        const float alpha = __fdiv_rn(ls[0], (float)n);
        for (int i = t; i < n; i += 256) {
            const float w = s_src[i];
            const float sg = (w > 0.f) ? 1.f : ((w < 0.f) ? -1.f : 0.f);
            const int d = (i % K) * W + (i / K);
            ws[off + d] = __fmul_rn(sg, alpha);
        }
    }
}

// ---------------------------------------------------------------------------
// conv_kernel: stages A-D, one image per block (R23 VERBATIM), writes v96 to
// the handoff slab. LDS 29,184 B, __launch_bounds__(256,8) (load-bearing).
// ---------------------------------------------------------------------------
__global__ __launch_bounds__(256, 8) void conv_kernel(
    const float* __restrict__ x, float* __restrict__ ws)
{
    __shared__ __align__(16) float s_x[16][20];        //  1280 B
    __shared__ __align__(16) float s_h1[16][14][20];   // 17920 B
    __shared__ float s_h2[16 * 156];                   //  9984 B (stride-13 rows)

    const int b = blockIdx.x;
    const int t = threadIdx.x;

    // ---- Stage A: input act-quant (accumulation-free -> hard round) ----
    {
        const float v = x[b * 256 + t];
        float m = fabsf(v);
        #pragma unroll
        for (int msk = 8; msk >= 1; msk >>= 1) m = fmaxf(m, __shfl_xor(m, msk, 16));
        const float s = __fdiv_rn(127.0f, fmaxf(m, 1e-5f));
        float q = rintf(__fmul_rn(v, s));
        q = fminf(fmaxf(q, -128.f), 127.f);
        s_x[t >> 4][t & 15] = __fdiv_rn(q, s);
    }
    __syncthreads();

    // ---- Stage B: conv1 (1->16, 3x3) + ReLU + row quant ----
    if (t < 224) {
        const int oc = t / 14, oh = t % 14;
        const float* __restrict__ wg = ws + OFF_W1 + oc * 12;
        const float4 wv0 = *(const float4*)&wg[0];
        const float4 wv1 = *(const float4*)&wg[4];
        const float  w8  = wg[8];
        const float wr[9] = {wv0.x, wv0.y, wv0.z, wv0.w,
                             wv1.x, wv1.y, wv1.z, wv1.w, w8};
        float acc[14];
        #pragma unroll
        for (int ow = 0; ow < 14; ++ow) acc[ow] = 0.f;
        #pragma unroll
        for (int kh = 0; kh < 3; ++kh) {
            float A[16];
            *(float4*)&A[0]  = *(const float4*)&s_x[oh + kh][0];
            *(float4*)&A[4]  = *(const float4*)&s_x[oh + kh][4];
            *(float4*)&A[8]  = *(const float4*)&s_x[oh + kh][8];
            *(float4*)&A[12] = *(const float4*)&s_x[oh + kh][12];
            #pragma unroll
            for (int kw = 0; kw < 3; ++kw) {
                const float wk = wr[kh * 3 + kw];
                #pragma unroll
                for (int ow = 0; ow < 14; ++ow)
                    acc[ow] = __fmaf_rn(A[ow + kw], wk, acc[ow]);
            }
        }
        float mx = 0.f;
        #pragma unroll
        for (int ow = 0; ow < 14; ++ow) { acc[ow] = fmaxf(acc[ow], 0.f); mx = fmaxf(mx, acc[ow]); }
        const float s = __fdiv_rn(127.0f, fmaxf(mx, 1e-5f));
        float q[14];
        #pragma unroll
        for (int ow = 0; ow < 14; ++ow) q[ow] = quantq(acc[ow], s);
        *(float4*)&s_h1[oc][oh][0]  = *(const float4*)&q[0];
        *(float4*)&s_h1[oc][oh][4]  = *(const float4*)&q[4];
        *(float4*)&s_h1[oc][oh][8]  = *(const float4*)&q[8];
        *(float2*)&s_h1[oc][oh][12] = *(const float2*)&q[12];
    }
    __syncthreads();

    // ---- Stage C: conv1b (16->16, 3x3) + ReLU + row quant ----
    if (t < 192) {
        const int oc = t / 12, oh = t % 12;
        const float* __restrict__ wg = ws + OFF_W1B + oc * 192;
        float acc[12];
        #pragma unroll
        for (int i = 0; i < 12; ++i) acc[i] = 0.f;
        for (int ic = 0; ic < 16; ++ic) {
            const float4 wv0 = *(const float4*)&wg[ic * 12];
            const float4 wv1 = *(const float4*)&wg[ic * 12 + 4];
            const float  w8  = wg[ic * 12 + 8];
            const float wr[9] = {wv0.x, wv0.y, wv0.z, wv0.w,
                                 wv1.x, wv1.y, wv1.z, wv1.w, w8};
            #pragma unroll
            for (int kh = 0; kh < 3; ++kh) {
                float A[14];
                *(float4*)&A[0]  = *(const float4*)&s_h1[ic][oh + kh][0];
                *(float4*)&A[4]  = *(const float4*)&s_h1[ic][oh + kh][4];
                *(float4*)&A[8]  = *(const float4*)&s_h1[ic][oh + kh][8];
                *(float2*)&A[12] = *(const float2*)&s_h1[ic][oh + kh][12];
                #pragma unroll
                for (int kw = 0; kw < 3; ++kw) {
                    const float w = wr[kh * 3 + kw];
                    #pragma unroll
                    for (int ow = 0; ow < 12; ++ow)
                        acc[ow] = __fmaf_rn(A[ow + kw], w, acc[ow]);
                }
            }
        }
        float mx = 0.f;
        #pragma unroll
        for (int ow = 0; ow < 12; ++ow) { acc[ow] = fmaxf(acc[ow], 0.f); mx = fmaxf(mx, acc[ow]); }
        const float s = __fdiv_rn(127.0f, fmaxf(mx, 1e-5f));
        const int hb = oc * 156 + oh * 13;
        #pragma unroll
        for (int ow = 0; ow < 12; ++ow)
            s_h2[hb + ow] = quantq(acc[ow], s);
    }
    __syncthreads();

    // ---- Stage D: conv2 grouped binary (16 g x 6 oc, 12x12) + ReLU ----
    if (t < 96) {
        const int g = t / 6;
        const float* __restrict__ wp = ws + OFF_W2;  // [k=144][96 oc]
        float acc = 0.f;
        #pragma unroll
        for (int r = 0; r < 12; ++r) {
            const int hb = g * 156 + r * 13;
            #pragma unroll
            for (int c = 0; c < 12; ++c)
                acc = __fmaf_rn(s_h2[hb + c], wp[(r * 12 + c) * 96 + t], acc);
        }
        ws[OFF_V96 + b * 96 + t] = fmaxf(acc, 0.f);   // global handoff
    }
}

// ---------------------------------------------------------------------------
// fc_kernel: 4 waves per block, each wave owns one image; mean-reduce done
// in-register via shfl chains preserving the exact numpy-pairwise order.
// LDS 1,536 B. (R23 verbatim)
// ---------------------------------------------------------------------------
__global__ __launch_bounds__(256) void fc_kernel(
    const float* __restrict__ ws, float* __restrict__ out, int nimg)
{
    __shared__ float s_q[4][96];

    const int t = threadIdx.x;
    const int w = t >> 6;      // wave id = image slot
    const int l = t & 63;      // lane within wave
    const int j = l & 7;       // r8 slot this lane reproduces
    const int img = blockIdx.x * 4 + w;
    if (img >= nimg) return;

    const float* __restrict__ v96 = ws + OFF_V96 + img * 96;

    // ---- Stage E: fc1 (96->64) ----
    float u;   // current activation vector element (lane l holds element l)
    {
        const float va = v96[l];
        const float vb = (l < 32) ? v96[64 + l] : 0.f;
        const float asq = __fmul_rn(va, va);     // t96[l]
        const float bsq = __fmul_rn(vb, vb);     // t96[64+l] (valid l<32)
        // r8[j] = t[j] + t[j+8] + ... + t[j+88], serial left-assoc (exact order):
        float r = __shfl(asq, j, 64);
        #pragma unroll
        for (int m2 = 1; m2 < 8; ++m2) r = __fadd_rn(r, __shfl(asq, j + 8 * m2, 64));
        #pragma unroll
        for (int m2 = 0; m2 < 4; ++m2) r = __fadd_rn(r, __shfl(bsq, j + 8 * m2, 64));
        // c = ((r0+r1)+(r2+r3)) + ((r4+r5)+(r6+r7)) via commutative butterfly:
        float c = __fadd_rn(r, __shfl_xor(r, 1, 64));
        c = __fadd_rn(c, __shfl_xor(c, 2, 64));
        c = __fadd_rn(c, __shfl_xor(c, 4, 64));
        const float mean = __fdiv_rn(c, 96.0f);
        const float bc1 = __fdiv_rn(1.0f, __fsqrt_rn(__fadd_rn(mean, 1e-6f)));
        const float n0 = __fmul_rn(va, bc1);
        const float n1 = __fmul_rn(vb, bc1);       // valid for l<32
        float m = n0;
        if (l < 32) m = fmaxf(m, n1);
        #pragma unroll
        for (int msk = 32; msk >= 1; msk >>= 1) m = fmaxf(m, __shfl_xor(m, msk, 64));
        const float s2 = __fdiv_rn(127.0f, fmaxf(m, 1e-5f));
        s_q[w][l] = quantq(n0, s2);
        if (l < 32) s_q[w][64 + l] = quantq(n1, s2);
        const float* __restrict__ wp = ws + OFF_F1;  // [k=96][64 o]
        float acc = 0.f;
        for (int k = 0; k < 96; ++k) acc = __fmaf_rn(s_q[w][k], wp[k * 64 + l], acc);
        u = fmaxf(acc, 0.f);
    }

    // ---- Stages F,G: fc2, fc3 (64->64) ----
    #pragma unroll 1
    for (int stage = 0; stage < 2; ++stage) {
        const int woff = stage == 0 ? OFF_F2 : OFF_F3;
        const float usq = __fmul_rn(u, u);
        // r8[j] = t[j] + t[j+8] + ... + t[j+56], serial left-assoc:
        float r = __shfl(usq, j, 64);
        #pragma unroll
        for (int m2 = 1; m2 < 8; ++m2) r = __fadd_rn(r, __shfl(usq, j + 8 * m2, 64));
        float c = __fadd_rn(r, __shfl_xor(r, 1, 64));
        c = __fadd_rn(c, __shfl_xor(c, 2, 64));
        c = __fadd_rn(c, __shfl_xor(c, 4, 64));
        const float mean = __fdiv_rn(c, 64.0f);
        const float bc1 = __fdiv_rn(1.0f, __fsqrt_rn(__fadd_rn(mean, 1e-6f)));
        const float n0 = __fmul_rn(u, bc1);
        float m = n0;
        #pragma unroll
        for (int msk = 32; msk >= 1; msk >>= 1) m = fmaxf(m, __shfl_xor(m, msk, 64));
        const float s2 = __fdiv_rn(127.0f, fmaxf(m, 1e-5f));
        s_q[w][l] = quantq(n0, s2);
        const float* __restrict__ wp = ws + woff;    // [k=64][64 o]
        float acc = 0.f;
        for (int k = 0; k < 64; ++k) acc = __fmaf_rn(s_q[w][k], wp[k * 64 + l], acc);
        u = fmaxf(acc, 0.f);
    }

    // ---- Stage H: fcl (64->10), no ReLU ----
    {
        const float usq = __fmul_rn(u, u);
        float r = __shfl(usq, j, 64);
        #pragma unroll
        for (int m2 = 1; m2 < 8; ++m2) r = __fadd_rn(r, __shfl(usq, j + 8 * m2, 64));
        float c = __fadd_rn(r, __shfl_xor(r, 1, 64));
        c = __fadd_rn(c, __shfl_xor(c, 2, 64));
        c = __fadd_rn(c, __shfl_xor(c, 4, 64));
        const float mean = __fdiv_rn(c, 64.0f);
        const float bc1 = __fdiv_rn(1.0f, __fsqrt_rn(__fadd_rn(mean, 1e-6f)));
        const float n0 = __fmul_rn(u, bc1);
        float m = n0;
        #pragma unroll
        for (int msk = 32; msk >= 1; msk >>= 1) m = fmaxf(m, __shfl_xor(m, msk, 64));
        const float s2 = __fdiv_rn(127.0f, fmaxf(m, 1e-5f));
        s_q[w][l] = quantq(n0, s2);
        const int to = (l < 10) ? l : 9;             // clamp: avoid OOB reads
        const float* __restrict__ wp = ws + OFF_FL;  // [k=64][10 o]
        float acc = 0.f;
        for (int k = 0; k < 64; ++k) acc = __fmaf_rn(s_q[w][k], wp[k * 10 + to], acc);
        if (l < 10) out[img * 10 + l] = acc;
    }
}

extern "C" void kernel_launch(void* const* d_in, const int* in_sizes, int n_in,
                              void* d_out, int out_size, void* d_ws, size_t ws_size,
                              hipStream_t stream) {
    const float* x   = (const float*)d_in[0];
    const float* w1  = (const float*)d_in[1];
    const float* w1b = (const float*)d_in[2];
    const float* w2  = (const float*)d_in[3];
    const float* f1  = (const float*)d_in[4];
    const float* f2  = (const float*)d_in[5];
    const float* f3  = (const float*)d_in[6];
    const float* fl  = (const float*)d_in[7];
    float* out = (float*)d_out;
    float* ws  = (float*)d_ws;

    const int B = in_sizes[0] / 256;  // 8192

    wq_kernel<<<7, 256, 0, stream>>>(w1, w1b, w2, f1, f2, f3, fl, ws);
    conv_kernel<<<B, 256, 0, stream>>>(x, ws);
    fc_kernel<<<(B + 3) / 4, 256, 0, stream>>>(ws, out, B);
}

// Round 13
// 225.837 us; speedup vs baseline: 1.1246x; 1.0068x over previous
//
#include <hip/hip_runtime.h>
#include <math.h>

// ---------------------------------------------------------------------------
// BitNet-style MNIST forward, STRICT-FP32, tie-neutralized act-quant (R14).
// R27 = R23 EXACT RESTORATION (measured best: 222.9us total).
//
// Final configuration ledger:
//  * wq_kernel: simple form (R26's LDS staging measured neutral-to-worse ->
//    reverted; wq is not a meaningful cost).
//  * conv_kernel: R23 form. 135.7us @ ~80% VALUBusy. Structural plateau:
//    FMA stream at lane-minimum (5184 wave-insts/image stage C); occupancy
//    null (R19/R24); narrow-LDS null (R24); reg-headroom null (R25);
//    __launch_bounds__(256,8) is load-bearing for LDS codegen (R25: (256,4)
//    tripled bank conflicts at identical VGPR count).
//  * fc_kernel: R23 shuffle-reduce form (order-exact numpy-pairwise chains).
//    Further fc parallelization would change summation order -> absmax risk.
//  * Phase split (R22) stands: conv full-wave-packed, fc gets TLP from 2048
//    independent blocks, no single-wave tail.
// ---------------------------------------------------------------------------

#define OFF_W1   0        // 16 oc x 12      = 192   ([oc][k], k padded 9->12)
#define OFF_W1B  192      // 16 oc x 16 x 12 = 3072  ([oc][ic*12+k])
#define OFF_W2   3264     // 96*1*12*12 = 13824 (TRANSPOSED: [k=144][96 oc])
#define OFF_F1   17088    // 64*96      = 6144  (TRANSPOSED: [k=96][64 o])
#define OFF_F2   23232    // 64*64      = 4096  (TRANSPOSED: [k=64][64 o])
#define OFF_F3   27328    // 64*64      = 4096  (TRANSPOSED: [k=64][64 o])
#define OFF_FL   31424    // 10*64      = 640   (TRANSPOSED: [k=64][10 o])
#define OFF_V96  32768    // 8192 x 96 activation slab (phase handoff)

#define EPS_TIE  3e-5f    // code-units half-width of the tie band

// Tie-neutralized quantized real value for v >= 0 (post-ReLU / normed >= 0).
__device__ __forceinline__ float quantq(float v, float s) {
    const float u  = __fmul_rn(v, s);
    const float fl = floorf(u);
    const float fr = __fsub_rn(u, fl);                 // exact
    float q;
    if (fabsf(__fsub_rn(fr, 0.5f)) < EPS_TIE) q = __fadd_rn(fl, 0.5f);
    else                                      q = rintf(u);
    q = fminf(q, 127.f);
    return __fdiv_rn(q, s);
}

// numpy pairwise leaf (n <= 128): 8 unrolled accumulators over |p[i]|.
__device__ __forceinline__ float leaf_abs_sum(const float* __restrict__ p, int n) {
    float r[8];
    #pragma unroll
    for (int j = 0; j < 8; ++j) r[j] = fabsf(p[j]);
    const int nb = n & ~7;
    for (int i = 8; i < nb; i += 8) {
        #pragma unroll
        for (int j = 0; j < 8; ++j) r[j] = __fadd_rn(r[j], fabsf(p[i + j]));
    }
    float c = __fadd_rn(__fadd_rn(__fadd_rn(r[0], r[1]), __fadd_rn(r[2], r[3])),
                        __fadd_rn(__fadd_rn(r[4], r[5]), __fadd_rn(r[6], r[7])));
    for (int i = nb; i < n; ++i) c = __fadd_rn(c, fabsf(p[i]));
    return c;
}

// ---------------------------------------------------------------------------
// Weight quantization: 7 blocks, one per tensor. (R23/R16 form)
// ---------------------------------------------------------------------------
__global__ __launch_bounds__(256) void wq_kernel(
    const float* __restrict__ w1, const float* __restrict__ w1b,
    const float* __restrict__ w2, const float* __restrict__ f1,
    const float* __restrict__ f2, const float* __restrict__ f3,
    const float* __restrict__ fl, float* __restrict__ ws)
{
    __shared__ float red[256];
    __shared__ float ls[128];
    const int blk = blockIdx.x, t = threadIdx.x;

    const float* src; int n; int mode; int off; int K; int W;
    switch (blk) {
        case 0:  src = w1;  n = 144;   mode = 0; off = OFF_W1;  K = 0;   W = 0;  break;
        case 1:  src = w1b; n = 2304;  mode = 0; off = OFF_W1B; K = 0;   W = 0;  break;
        case 2:  src = w2;  n = 13824; mode = 1; off = OFF_W2;  K = 144; W = 96; break;
        case 3:  src = f1;  n = 6144;  mode = 1; off = OFF_F1;  K = 96;  W = 64; break;
        case 4:  src = f2;  n = 4096;  mode = 1; off = OFF_F2;  K = 64;  W = 64; break;
        case 5:  src = f3;  n = 4096;  mode = 1; off = OFF_F3;  K = 64;  W = 64; break;
        default: src = fl;  n = 640;   mode = 1; off = OFF_FL;  K = 64;  W = 10; break;
    }

    if (mode == 0) {
        float p = 0.f;
        for (int i = t; i < n; i += 256) p = fmaxf(p, fabsf(src[i]));
        red[t] = p;
        __syncthreads();
        for (int s = 128; s > 0; s >>= 1) {
            if (t < s) red[t] = fmaxf(red[t], red[t + s]);
            __syncthreads();
        }
        const float s = __fdiv_rn(127.0f, fmaxf(red[0], 1e-5f));
        for (int i = t; i < n; i += 256) {
            float q = rintf(__fmul_rn(src[i], s));
            q = fminf(fmaxf(q, -128.f), 127.f);
            int d;
            if (blk == 0) d = (i / 9) * 12 + (i % 9);
            else          { const int oc = i / 144, k = i % 144;
                            d = oc * 192 + (k / 9) * 12 + (k % 9); }
            ws[off + d] = __fdiv_rn(q, s);
        }
    } else {
        int nleaf, loff, lsz;
        switch (n) {
            case 13824: nleaf = 128; loff = (t >> 1) * 216 + (t & 1) * 104;
                        lsz = (t & 1) ? 112 : 104; break;
            case 6144:  nleaf = 64;  loff = t * 96;  lsz = 96;  break;
            case 4096:  nleaf = 32;  loff = t * 128; lsz = 128; break;
            default:    nleaf = 8;   loff = t * 80;  lsz = 80;  break;  // 640
        }
        if (t < nleaf) ls[t] = leaf_abs_sum(src + loff, lsz);
        __syncthreads();
        for (int m = nleaf >> 1; m >= 1; m >>= 1) {
            float v = 0.f;
            if (t < m) v = __fadd_rn(ls[2 * t], ls[2 * t + 1]);
            __syncthreads();
            if (t < m) ls[t] = v;
            __syncthreads();
        }
        const float alpha = __fdiv_rn(ls[0], (float)n);
        for (int i = t; i < n; i += 256) {
            const float w = src[i];
            const float sg = (w > 0.f) ? 1.f : ((w < 0.f) ? -1.f : 0.f);
            const int d = (i % K) * W + (i / K);
            ws[off + d] = __fmul_rn(sg, alpha);
        }
    }
}

// ---------------------------------------------------------------------------
// conv_kernel: stages A-D, one image per block, writes v96 to the handoff
// slab. LDS 29,184 B, __launch_bounds__(256,8). (R23 verbatim)
// ---------------------------------------------------------------------------
__global__ __launch_bounds__(256, 8) void conv_kernel(
    const float* __restrict__ x, float* __restrict__ ws)
{
    __shared__ __align__(16) float s_x[16][20];        //  1280 B
    __shared__ __align__(16) float s_h1[16][14][20];   // 17920 B
    __shared__ float s_h2[16 * 156];                   //  9984 B (stride-13 rows)

    const int b = blockIdx.x;
    const int t = threadIdx.x;

    // ---- Stage A: input act-quant (accumulation-free -> hard round) ----
    {
        const float v = x[b * 256 + t];
        float m = fabsf(v);
        #pragma unroll
        for (int msk = 8; msk >= 1; msk >>= 1) m = fmaxf(m, __shfl_xor(m, msk, 16));
        const float s = __fdiv_rn(127.0f, fmaxf(m, 1e-5f));
        float q = rintf(__fmul_rn(v, s));
        q = fminf(fmaxf(q, -128.f), 127.f);
        s_x[t >> 4][t & 15] = __fdiv_rn(q, s);
    }
    __syncthreads();

    // ---- Stage B: conv1 (1->16, 3x3) + ReLU + row quant ----
    if (t < 224) {
        const int oc = t / 14, oh = t % 14;
        const float* __restrict__ wg = ws + OFF_W1 + oc * 12;
        const float4 wv0 = *(const float4*)&wg[0];
        const float4 wv1 = *(const float4*)&wg[4];
        const float  w8  = wg[8];
        const float wr[9] = {wv0.x, wv0.y, wv0.z, wv0.w,
                             wv1.x, wv1.y, wv1.z, wv1.w, w8};
        float acc[14];
        #pragma unroll
        for (int ow = 0; ow < 14; ++ow) acc[ow] = 0.f;
        #pragma unroll
        for (int kh = 0; kh < 3; ++kh) {
            float A[16];
            *(float4*)&A[0]  = *(const float4*)&s_x[oh + kh][0];
            *(float4*)&A[4]  = *(const float4*)&s_x[oh + kh][4];
            *(float4*)&A[8]  = *(const float4*)&s_x[oh + kh][8];
            *(float4*)&A[12] = *(const float4*)&s_x[oh + kh][12];
            #pragma unroll
            for (int kw = 0; kw < 3; ++kw) {
                const float wk = wr[kh * 3 + kw];
                #pragma unroll
                for (int ow = 0; ow < 14; ++ow)
                    acc[ow] = __fmaf_rn(A[ow + kw], wk, acc[ow]);
            }
        }
        float mx = 0.f;
        #pragma unroll
        for (int ow = 0; ow < 14; ++ow) { acc[ow] = fmaxf(acc[ow], 0.f); mx = fmaxf(mx, acc[ow]); }
        const float s = __fdiv_rn(127.0f, fmaxf(mx, 1e-5f));
        float q[14];
        #pragma unroll
        for (int ow = 0; ow < 14; ++ow) q[ow] = quantq(acc[ow], s);
        *(float4*)&s_h1[oc][oh][0]  = *(const float4*)&q[0];
        *(float4*)&s_h1[oc][oh][4]  = *(const float4*)&q[4];
        *(float4*)&s_h1[oc][oh][8]  = *(const float4*)&q[8];
        *(float2*)&s_h1[oc][oh][12] = *(const float2*)&q[12];
    }
    __syncthreads();

    // ---- Stage C: conv1b (16->16, 3x3) + ReLU + row quant ----
    if (t < 192) {
        const int oc = t / 12, oh = t % 12;
        const float* __restrict__ wg = ws + OFF_W1B + oc * 192;
        float acc[12];
        #pragma unroll
        for (int i = 0; i < 12; ++i) acc[i] = 0.f;
        for (int ic = 0; ic < 16; ++ic) {
            const float4 wv0 = *(const float4*)&wg[ic * 12];
            const float4 wv1 = *(const float4*)&wg[ic * 12 + 4];
            const float  w8  = wg[ic * 12 + 8];
            const float wr[9] = {wv0.x, wv0.y, wv0.z, wv0.w,
                                 wv1.x, wv1.y, wv1.z, wv1.w, w8};
            #pragma unroll
            for (int kh = 0; kh < 3; ++kh) {
                float A[14];
                *(float4*)&A[0]  = *(const float4*)&s_h1[ic][oh + kh][0];
                *(float4*)&A[4]  = *(const float4*)&s_h1[ic][oh + kh][4];
                *(float4*)&A[8]  = *(const float4*)&s_h1[ic][oh + kh][8];
                *(float2*)&A[12] = *(const float2*)&s_h1[ic][oh + kh][12];
                #pragma unroll
                for (int kw = 0; kw < 3; ++kw) {
                    const float w = wr[kh * 3 + kw];
                    #pragma unroll
                    for (int ow = 0; ow < 12; ++ow)
                        acc[ow] = __fmaf_rn(A[ow + kw], w, acc[ow]);
                }
            }
        }
        float mx = 0.f;
        #pragma unroll
        for (int ow = 0; ow < 12; ++ow) { acc[ow] = fmaxf(acc[ow], 0.f); mx = fmaxf(mx, acc[ow]); }
        const float s = __fdiv_rn(127.0f, fmaxf(mx, 1e-5f));
        const int hb = oc * 156 + oh * 13;
        #pragma unroll
        for (int ow = 0; ow < 12; ++ow)
            s_h2[hb + ow] = quantq(acc[ow], s);
    }
    __syncthreads();

    // ---- Stage D: conv2 grouped binary (16 g x 6 oc, 12x12) + ReLU ----
    if (t < 96) {
        const int g = t / 6;
        const float* __restrict__ wp = ws + OFF_W2;  // [k=144][96 oc]
        float acc = 0.f;
        #pragma unroll
        for (int r = 0; r < 12; ++r) {
            const int hb = g * 156 + r * 13;
            #pragma unroll
            for (int c = 0; c < 12; ++c)
                acc = __fmaf_rn(s_h2[hb + c], wp[(r * 12 + c) * 96 + t], acc);
        }
        ws[OFF_V96 + b * 96 + t] = fmaxf(acc, 0.f);   // global handoff
    }
}

// ---------------------------------------------------------------------------
// fc_kernel: 4 waves per block, each wave owns one image; mean-reduce done
// in-register via shfl chains preserving the exact numpy-pairwise order.
// LDS 1,536 B. (R23 verbatim)
// ---------------------------------------------------------------------------
__global__ __launch_bounds__(256) void fc_kernel(
    const float* __restrict__ ws, float* __restrict__ out, int nimg)
{
    __shared__ float s_q[4][96];

    const int t = threadIdx.x;
    const int w = t >> 6;      // wave id = image slot
    const int l = t & 63;      // lane within wave
    const int j = l & 7;       // r8 slot this lane reproduces
    const int img = blockIdx.x * 4 + w;
    if (img >= nimg) return;

    const float* __restrict__ v96 = ws + OFF_V96 + img * 96;

    // ---- Stage E: fc1 (96->64) ----
    float u;   // current activation vector element (lane l holds element l)
    {
        const float va = v96[l];
        const float vb = (l < 32) ? v96[64 + l] : 0.f;
        const float asq = __fmul_rn(va, va);     // t96[l]
        const float bsq = __fmul_rn(vb, vb);     // t96[64+l] (valid l<32)
        // r8[j] = t[j] + t[j+8] + ... + t[j+88], serial left-assoc (exact order):
        float r = __shfl(asq, j, 64);
        #pragma unroll
        for (int m2 = 1; m2 < 8; ++m2) r = __fadd_rn(r, __shfl(asq, j + 8 * m2, 64));
        #pragma unroll
        for (int m2 = 0; m2 < 4; ++m2) r = __fadd_rn(r, __shfl(bsq, j + 8 * m2, 64));
        // c = ((r0+r1)+(r2+r3)) + ((r4+r5)+(r6+r7)) via commutative butterfly:
        float c = __fadd_rn(r, __shfl_xor(r, 1, 64));
        c = __fadd_rn(c, __shfl_xor(c, 2, 64));
        c = __fadd_rn(c, __shfl_xor(c, 4, 64));
        const float mean = __fdiv_rn(c, 96.0f);
        const float bc1 = __fdiv_rn(1.0f, __fsqrt_rn(__fadd_rn(mean, 1e-6f)));
        const float n0 = __fmul_rn(va, bc1);
        const float n1 = __fmul_rn(vb, bc1);       // valid for l<32
        float m = n0;
        if (l < 32) m = fmaxf(m, n1);
        #pragma unroll
        for (int msk = 32; msk >= 1; msk >>= 1) m = fmaxf(m, __shfl_xor(m, msk, 64));
        const float s2 = __fdiv_rn(127.0f, fmaxf(m, 1e-5f));
        s_q[w][l] = quantq(n0, s2);
        if (l < 32) s_q[w][64 + l] = quantq(n1, s2);
        const float* __restrict__ wp = ws + OFF_F1;  // [k=96][64 o]
        float acc = 0.f;
        for (int k = 0; k < 96; ++k) acc = __fmaf_rn(s_q[w][k], wp[k * 64 + l], acc);
        u = fmaxf(acc, 0.f);
    }

    // ---- Stages F,G: fc2, fc3 (64->64) ----
    #pragma unroll 1
    for (int stage = 0; stage < 2; ++stage) {
        const int woff = stage == 0 ? OFF_F2 : OFF_F3;
        const float usq = __fmul_rn(u, u);
        // r8[j] = t[j] + t[j+8] + ... + t[j+56], serial left-assoc:
        float r = __shfl(usq, j, 64);
        #pragma unroll
        for (int m2 = 1; m2 < 8; ++m2) r = __fadd_rn(r, __shfl(usq, j + 8 * m2, 64));
        float c = __fadd_rn(r, __shfl_xor(r, 1, 64));
        c = __fadd_rn(c, __shfl_xor(c, 2, 64));
        c = __fadd_rn(c, __shfl_xor(c, 4, 64));
        const float mean = __fdiv_rn(c, 64.0f);
        const float bc1 = __fdiv_rn(1.0f, __fsqrt_rn(__fadd_rn(mean, 1e-6f)));
        const float n0 = __fmul_rn(u, bc1);
        float m = n0;
        #pragma unroll
        for (int msk = 32; msk >= 1; msk >>= 1) m = fmaxf(m, __shfl_xor(m, msk, 64));
        const float s2 = __fdiv_rn(127.0f, fmaxf(m, 1e-5f));
        s_q[w][l] = quantq(n0, s2);
        const float* __restrict__ wp = ws + woff;    // [k=64][64 o]
        float acc = 0.f;
        for (int k = 0; k < 64; ++k) acc = __fmaf_rn(s_q[w][k], wp[k * 64 + l], acc);
        u = fmaxf(acc, 0.f);
    }

    // ---- Stage H: fcl (64->10), no ReLU ----
    {
        const float usq = __fmul_rn(u, u);
        float r = __shfl(usq, j, 64);
        #pragma unroll
        for (int m2 = 1; m2 < 8; ++m2) r = __fadd_rn(r, __shfl(usq, j + 8 * m2, 64));
        float c = __fadd_rn(r, __shfl_xor(r, 1, 64));
        c = __fadd_rn(c, __shfl_xor(c, 2, 64));
        c = __fadd_rn(c, __shfl_xor(c, 4, 64));
        const float mean = __fdiv_rn(c, 64.0f);
        const float bc1 = __fdiv_rn(1.0f, __fsqrt_rn(__fadd_rn(mean, 1e-6f)));
        const float n0 = __fmul_rn(u, bc1);
        float m = n0;
        #pragma unroll
        for (int msk = 32; msk >= 1; msk >>= 1) m = fmaxf(m, __shfl_xor(m, msk, 64));
        const float s2 = __fdiv_rn(127.0f, fmaxf(m, 1e-5f));
        s_q[w][l] = quantq(n0, s2);
        const int to = (l < 10) ? l : 9;             // clamp: avoid OOB reads
        const float* __restrict__ wp = ws + OFF_FL;  // [k=64][10 o]
        float acc = 0.f;
        for (int k = 0; k < 64; ++k) acc = __fmaf_rn(s_q[w][k], wp[k * 10 + to], acc);
        if (l < 10) out[img * 10 + l] = acc;
    }
}

extern "C" void kernel_launch(void* const* d_in, const int* in_sizes, int n_in,
                              void* d_out, int out_size, void* d_ws, size_t ws_size,
                              hipStream_t stream) {
    const float* x   = (const float*)d_in[0];
    const float* w1  = (const float*)d_in[1];
    const float* w1b = (const float*)d_in[2];
    const float* w2  = (const float*)d_in[3];
    const float* f1  = (const float*)d_in[4];
    const float* f2  = (const float*)d_in[5];
    const float* f3  = (const float*)d_in[6];
    const float* fl  = (const float*)d_in[7];
    float* out = (float*)d_out;
    float* ws  = (float*)d_ws;

    const int B = in_sizes[0] / 256;  // 8192

    wq_kernel<<<7, 256, 0, stream>>>(w1, w1b, w2, f1, f2, f3, fl, ws);
    conv_kernel<<<B, 256, 0, stream>>>(x, ws);
    fc_kernel<<<(B + 3) / 4, 256, 0, stream>>>(ws, out, B);
}